// Round 9
// baseline (172.443 us; speedup 1.0000x reference)
//
#include <hip/hip_runtime.h>
#include <hip/hip_bf16.h>
#include <stdint.h>

#define N_TOK 8192
#define DDIM  128

typedef _Float16 half2v __attribute__((ext_vector_type(2)));
typedef _Float16 half4v __attribute__((ext_vector_type(4)));
typedef _Float16 half8v __attribute__((ext_vector_type(8)));
typedef __fp16  fp16x2 __attribute__((ext_vector_type(2)));
typedef float f32x4 __attribute__((ext_vector_type(4)));
typedef half4v half4_ma __attribute__((may_alias));
typedef half8v half8_ma __attribute__((may_alias));
typedef float4 float4_ma __attribute__((may_alias));

#define MFMA16 __builtin_amdgcn_mfma_f32_16x16x16f16   // legacy spelling
#define MFMA32 __builtin_amdgcn_mfma_f32_16x16x32_f16

// 1/sqrt(128) * log2(e): folded into Q so inner loop is a bare v_exp_f32
#define QSCALE (0.08838834764831845f * 1.4426950408889634f)

__device__ __forceinline__ half2v pkrtz(float a, float b) {
  return __builtin_bit_cast(half2v, __builtin_amdgcn_cvt_pkrtz(a, b));
}

#if __has_builtin(__builtin_amdgcn_fdot2)
__device__ __forceinline__ float dot2acc(half2v a, float c) {
  const fp16x2 ones = {(__fp16)1.f, (__fp16)1.f};
  return __builtin_amdgcn_fdot2(__builtin_bit_cast(fp16x2, a), ones, c, false);
}
#else
__device__ __forceinline__ float dot2acc(half2v a, float c) {
  return c + (float)a.x + (float)a.y;
}
#endif

__device__ __forceinline__ void gload_lds16(const _Float16* g, _Float16* l) {
  __builtin_amdgcn_global_load_lds(
      (const __attribute__((address_space(1))) void*)g,
      (__attribute__((address_space(3))) void*)l, 16, 0, 0);
}

// software grid barrier: safe because grid == 1 block/CU (co-resident).
__device__ __forceinline__ void grid_barrier(uint32_t* bar, uint32_t expected) {
  __syncthreads();
  if (threadIdx.x == 0) {
    __threadfence();   // release: flush this block's writes device-wide
    __hip_atomic_fetch_add(bar, 1u, __ATOMIC_RELEASE, __HIP_MEMORY_SCOPE_AGENT);
    while (__hip_atomic_load(bar, __ATOMIC_ACQUIRE, __HIP_MEMORY_SCOPE_AGENT) < expected)
      __builtin_amdgcn_s_sleep(2);
    __threadfence();   // acquire: invalidate stale lines before reads
  }
  __syncthreads();
}

// ======================= fused: prep -> flash -> combine ====================
// Persistent grid: 32*KS blocks x 512 threads, 64KB LDS, 1 block/CU (KS=8).
template<int KS>
__global__ __launch_bounds__(512, 1) void fused_attn(
    const float* __restrict__ x, float* __restrict__ out,
    _Float16* __restrict__ Qf, _Float16* __restrict__ Kf,
    _Float16* __restrict__ Vt, _Float16* __restrict__ Opart,
    float* __restrict__ Lsum, uint32_t* __restrict__ bar) {
  alignas(16) __shared__ _Float16 lds[32768];  // 64 KB, reused across phases

  const int tid = threadIdx.x;
  const int blk = blockIdx.x;
  const int nblk = gridDim.x;           // 32*KS

  // ---------------- phase 1: prep (Q/K transpose + V cast-copy) ------------
  {
    float* tbuf = (float*)lds;          // 2 teams x 32x33 floats
    const int team = tid >> 8, ttid = tid & 255;
    const int tx = ttid & 31, ty0 = ttid >> 5;
    // 2048 transpose tiles; nblk*2 teams; tile0 < stride so counts are uniform
    for (int tile = blk * 2 + team; tile < 2048; tile += nblk * 2) {
      const int pt = tile & 31, ct = (tile >> 5) & 3, z = tile >> 7;
      const int b = z >> 1, isQ = z & 1;
      const int c0 = (isQ ? 256 : 128) + ct * 32;
      const int p0 = pt * 32;
      float* t = tbuf + team * 1056;
      const float* src = x + ((size_t)b * 384 + c0) * 1024 + p0;
#pragma unroll
      for (int i = 0; i < 4; ++i)
        t[(ty0 + i * 8) * 33 + tx] = src[(ty0 + i * 8) * 1024 + tx];
      __syncthreads();
      _Float16* dst = isQ ? Qf : Kf;
      const float sc = isQ ? QSCALE : 1.f;
#pragma unroll
      for (int i = 0; i < 4; ++i) {
        const int ty = ty0 + i * 8;
        dst[((size_t)b * 1024 + p0 + ty) * DDIM + ct * 32 + tx] =
            (_Float16)(t[tx * 33 + ty] * sc);
      }
      __syncthreads();
    }
    // V: [128][8192] f16, one float4 per thread, grid-stride
    for (int i4 = (blk * 512 + tid) * 4; i4 < DDIM * N_TOK; i4 += nblk * 512 * 4) {
      const int v = i4 >> 13, n = i4 & 8191;
      const int b = n >> 10, p = n & 1023;
      const float4 s = *(const float4_ma*)(x + ((size_t)b * 384 + v) * 1024 + p);
      half4v h; h.x = (_Float16)s.x; h.y = (_Float16)s.y;
      h.z = (_Float16)s.z; h.w = (_Float16)s.w;
      *(half4_ma*)(Vt + (size_t)v * N_TOK + b * 1024 + p) = h;
    }
  }
  grid_barrier(bar + 0, nblk);

  // ---------------- phase 2: flash attention (R7 structure) ----------------
  {
    const int w = tid >> 6, lane = tid & 63;
    const int quad = lane >> 4, l16 = lane & 15;
    // KS=8: ks == XCD id (blk%8) -> each XCD touches one 1024-key K/V slice
    const int ks = (KS == 16) ? (((blk & 7) << 1) | (blk >> 8)) : (blk & (KS - 1));
    const int qt = (blk / KS == 0 ? (blk >> 3) : (blk >> 3)) & 31;  // blk>>3 for KS=8/16
    const int kp = N_TOK / KS;
    const int chunks = kp >> 6;
    const int k0 = ks * kp;
    const int q0 = ((blk >> 3) & 31) * 256;
    (void)qt;

    half8v qf[2][4];
#pragma unroll
    for (int t2 = 0; t2 < 2; ++t2) {
      const _Float16* qp = Qf + (size_t)(q0 + w * 32 + t2 * 16 + l16) * DDIM + quad * 8;
#pragma unroll
      for (int kb = 0; kb < 4; ++kb) qf[t2][kb] = *(const half8_ma*)(qp + kb * 32);
    }

    f32x4 O[2][8];
#pragma unroll
    for (int t2 = 0; t2 < 2; ++t2)
#pragma unroll
      for (int vb = 0; vb < 8; ++vb) O[t2][vb] = (f32x4){0.f, 0.f, 0.f, 0.f};
    float ls[2] = {0.f, 0.f};

    const _Float16* srcK[2];
    const _Float16* srcV[2];
    int slot[2];
#pragma unroll
    for (int j = 0; j < 2; ++j) {
      const int chi = w * 2 + j;                  // 0..15
      srcK[j] = Kf + (size_t)(k0 + lane) * DDIM + chi * 8;
      const int t = chi * 64 + lane;
      const int v = t >> 3, h = t & 7;
      const int hs = h ^ ((v >> 1) & 7);          // xor-swizzle granule
      srcV[j] = Vt + (size_t)v * N_TOK + k0 + hs * 8;
      slot[j] = chi * 512;
    }

#pragma unroll
    for (int j = 0; j < 2; ++j) {
      gload_lds16(srcK[j], lds + slot[j]);
      gload_lds16(srcV[j], lds + 8192 + slot[j]);
    }

    for (int ch = 0; ch < chunks; ++ch) {
      __syncthreads();
      _Float16* buf = lds + (ch & 1) * 16384;
      if (ch + 1 < chunks) {
        _Float16* nbuf = lds + ((ch + 1) & 1) * 16384;
        const int adv = (ch + 1) * 64;
#pragma unroll
        for (int j = 0; j < 2; ++j) {
          gload_lds16(srcK[j] + (size_t)adv * DDIM, nbuf + slot[j]);
          gload_lds16(srcV[j] + adv, nbuf + 8192 + slot[j]);
        }
      }
      const _Float16* Ksh = buf;
      const _Float16* Vsh = buf + 8192;

      f32x4 S[2][4];
#pragma unroll
      for (int t2 = 0; t2 < 2; ++t2)
#pragma unroll
        for (int cb = 0; cb < 4; ++cb) S[t2][cb] = (f32x4){0.f, 0.f, 0.f, 0.f};
#pragma unroll
      for (int kb = 0; kb < 4; ++kb) {
#pragma unroll
        for (int cb = 0; cb < 4; ++cb) {
          half8v kf = *(const half8_ma*)(Ksh + (((kb * 4 + quad) * 64) + cb * 16 + l16) * 8);
          S[0][cb] = MFMA32(kf, qf[0][kb], S[0][cb], 0, 0, 0);
          S[1][cb] = MFMA32(kf, qf[1][kb], S[1][cb], 0, 0, 0);
        }
      }

      half4v P[2][4];
#pragma unroll
      for (int t2 = 0; t2 < 2; ++t2) {
#pragma unroll
        for (int cb = 0; cb < 4; ++cb) {
          const float p0 = __builtin_amdgcn_exp2f(S[t2][cb][0]);
          const float p1 = __builtin_amdgcn_exp2f(S[t2][cb][1]);
          const float p2 = __builtin_amdgcn_exp2f(S[t2][cb][2]);
          const float p3 = __builtin_amdgcn_exp2f(S[t2][cb][3]);
          half2v lo = pkrtz(p0, p1);
          half2v hi = pkrtz(p2, p3);
          ls[t2] = dot2acc(lo, dot2acc(hi, ls[t2]));
          P[t2][cb] = __builtin_shufflevector(lo, hi, 0, 1, 2, 3);
        }
      }

#pragma unroll
      for (int cb = 0; cb < 4; ++cb) {
#pragma unroll
        for (int vb = 0; vb < 8; ++vb) {
          const int v = vb * 16 + l16;
          half4v vf = *(const half4_ma*)(Vsh + v * 64 + (((cb * 4 + quad) ^ (l16 & 14)) * 4));
          O[0][vb] = MFMA16(vf, P[0][cb], O[0][vb], 0, 0, 0);
          O[1][vb] = MFMA16(vf, P[1][cb], O[1][vb], 0, 0, 0);
        }
      }
    }

#pragma unroll
    for (int t2 = 0; t2 < 2; ++t2) {
      ls[t2] += __shfl_xor(ls[t2], 16, 64);
      ls[t2] += __shfl_xor(ls[t2], 32, 64);
    }
#pragma unroll
    for (int t2 = 0; t2 < 2; ++t2) {
      const float rl = 1.f / ls[t2];
      const int q = q0 + w * 32 + t2 * 16 + l16;
#pragma unroll
      for (int vb = 0; vb < 8; ++vb) {
#pragma unroll
        for (int r = 0; r < 4; ++r) {
          const int v = vb * 16 + quad * 4 + r;
          Opart[((size_t)ks * DDIM + v) * N_TOK + q] = (_Float16)(O[t2][vb][r] * rl);
        }
      }
    }
    if (lane < 16) {
#pragma unroll
      for (int t2 = 0; t2 < 2; ++t2)
        Lsum[(size_t)ks * N_TOK + q0 + w * 32 + t2 * 16 + lane] = ls[t2];
    }
  }
  grid_barrier(bar + 8, nblk);

  // ---------------- phase 3: combine (float4/thread, grid-stride) ----------
  for (int o4 = (blk * 512 + tid) * 4; o4 < N_TOK * DDIM; o4 += nblk * 512 * 4) {
    const int b = o4 >> 17, v = (o4 >> 10) & 127, p = o4 & 1023;
    const int q = (b << 10) | p;
    float4 num = make_float4(0.f, 0.f, 0.f, 0.f);
    float4 den = make_float4(0.f, 0.f, 0.f, 0.f);
#pragma unroll
    for (int s = 0; s < KS; ++s) {
      const float4 l = *(const float4_ma*)(Lsum + (size_t)s * N_TOK + q);
      const half4v ov = *(const half4_ma*)(Opart + ((size_t)s * DDIM + v) * N_TOK + q);
      num.x += l.x * (float)ov.x; num.y += l.y * (float)ov.y;
      num.z += l.z * (float)ov.z; num.w += l.w * (float)ov.w;
      den.x += l.x; den.y += l.y; den.z += l.z; den.w += l.w;
    }
    *(float4_ma*)(out + o4) =
        make_float4(num.x / den.x, num.y / den.y, num.z / den.z, num.w / den.w);
  }
}

// ---------------- launch ---------------------------------------------------
extern "C" void kernel_launch(void* const* d_in, const int* in_sizes, int n_in,
                              void* d_out, int out_size, void* d_ws, size_t ws_size,
                              hipStream_t stream) {
  const float* x = (const float*)d_in[0];
  float* out = (float*)d_out;
  char* ws = (char*)d_ws;

  // KS=8 layout: Qf 2MB | Kf 2MB | Vt 2MB | Opart 16MB | Lsum 256KB | bar 64B
  const int KS = 8;
  _Float16* Qf    = (_Float16*)(ws);
  _Float16* Kf    = (_Float16*)(ws + (2u << 20));
  _Float16* Vt    = (_Float16*)(ws + (4u << 20));
  _Float16* Opart = (_Float16*)(ws + (6u << 20));
  float*    Lsum  = (float*)(ws + (6u << 20) + (size_t)KS * (2u << 20));
  uint32_t* bar   = (uint32_t*)(ws + (6u << 20) + (size_t)KS * (2u << 20) + (1u << 20));

  // barrier counters must start at 0 every call (ws is re-poisoned to 0xAA)
  hipMemsetAsync(bar, 0, 64, stream);
  // 256 blocks x 512 thr, 64KB LDS -> 1 block/CU: co-residency guaranteed.
  fused_attn<8><<<dim3(32 * KS), dim3(512), 0, stream>>>(
      x, out, Qf, Kf, Vt, Opart, Lsum, bar);
}

// Round 10
// 163.147 us; speedup vs baseline: 1.0570x; 1.0570x over previous
//
#include <hip/hip_runtime.h>
#include <hip/hip_bf16.h>
#include <stdint.h>

#define N_TOK 8192
#define DDIM  128

typedef _Float16 half2v __attribute__((ext_vector_type(2)));
typedef _Float16 half4v __attribute__((ext_vector_type(4)));
typedef _Float16 half8v __attribute__((ext_vector_type(8)));
typedef __fp16  fp16x2 __attribute__((ext_vector_type(2)));
typedef float f32x4 __attribute__((ext_vector_type(4)));
typedef half4v half4_ma __attribute__((may_alias));
typedef half8v half8_ma __attribute__((may_alias));
typedef float4 float4_ma __attribute__((may_alias));

#define MFMA16 __builtin_amdgcn_mfma_f32_16x16x16f16   // legacy spelling
#define MFMA32 __builtin_amdgcn_mfma_f32_16x16x32_f16

// 1/sqrt(128) * log2(e): folded into Q so inner loop is a bare v_exp_f32
#define QSCALE (0.08838834764831845f * 1.4426950408889634f)

__device__ __forceinline__ half2v pkrtz(float a, float b) {
  return __builtin_bit_cast(half2v, __builtin_amdgcn_cvt_pkrtz(a, b));
}

#if __has_builtin(__builtin_amdgcn_fdot2)
__device__ __forceinline__ float dot2acc(half2v a, float c) {
  const fp16x2 ones = {(__fp16)1.f, (__fp16)1.f};
  return __builtin_amdgcn_fdot2(__builtin_bit_cast(fp16x2, a), ones, c, false);
}
#else
__device__ __forceinline__ float dot2acc(half2v a, float c) {
  return c + (float)a.x + (float)a.y;
}
#endif

__device__ __forceinline__ void gload_lds16(const _Float16* g, _Float16* l) {
  __builtin_amdgcn_global_load_lds(
      (const __attribute__((address_space(1))) void*)g,
      (__attribute__((address_space(3))) void*)l, 16, 0, 0);
}

// ---------------- fused prep: Q/K transpose + V copy (one launch) ----------
__global__ void prep_all(const float* __restrict__ x,
                         _Float16* __restrict__ Qf, _Float16* __restrict__ Kf,
                         _Float16* __restrict__ Vt) {
  __shared__ float t[32][33];
  const int blk = blockIdx.x, tid = threadIdx.x;
  if (blk < 2048) {
    const int pt = blk & 31, ct = (blk >> 5) & 3, z = blk >> 7;
    const int b = z >> 1, isQ = z & 1;
    const int c0 = (isQ ? 256 : 128) + ct * 32;
    const int p0 = pt * 32;
    const int tx = tid & 31, ty0 = tid >> 5;
    const float* src = x + ((size_t)b * 384 + c0) * 1024 + p0;
#pragma unroll
    for (int i = 0; i < 4; ++i)
      t[ty0 + i * 8][tx] = src[(ty0 + i * 8) * 1024 + tx];
    __syncthreads();
    _Float16* dst = isQ ? Qf : Kf;
    const float sc = isQ ? QSCALE : 1.f;
#pragma unroll
    for (int i = 0; i < 4; ++i) {
      const int ty = ty0 + i * 8;
      dst[((size_t)b * 1024 + p0 + ty) * DDIM + ct * 32 + tx] = (_Float16)(t[tx][ty] * sc);
    }
  } else {
    const int i4 = ((blk - 2048) * 256 + tid) * 4;
    const int v = i4 >> 13, n = i4 & 8191;
    const int b = n >> 10, p = n & 1023;
    const float4 s = *(const float4_ma*)(x + ((size_t)b * 384 + v) * 1024 + p);
    half4v h; h.x = (_Float16)s.x; h.y = (_Float16)s.y; h.z = (_Float16)s.z; h.w = (_Float16)s.w;
    *(half4_ma*)(Vt + (size_t)v * N_TOK + b * 1024 + p) = h;
  }
}

// ---------------- flash attention: QT=4/wave, 256 thr, XCD swizzle ---------
// 1-D grid of 32*KS blocks x 256 thr (4 waves x 64 qrows). 64KB LDS ->
// 2 blocks/CU. ks decoded so each XCD touches only KS/8 key-slices.
template<int KS>
__global__ __launch_bounds__(256, 2) void flash_attn(
    const _Float16* __restrict__ Qf, const _Float16* __restrict__ Kf,
    const _Float16* __restrict__ Vt, _Float16* __restrict__ Opart,
    float* __restrict__ Lsum) {
  alignas(16) __shared__ _Float16 lds[32768];  // 2 x (K 16KB + V 16KB)

  const int tid = threadIdx.x;
  const int w = tid >> 6, lane = tid & 63;
  const int quad = lane >> 4, l16 = lane & 15;
  const int blk = blockIdx.x;
  // XCD swizzle: blk&7 = XCD id; cluster ks per XCD for L2 locality
  const int ks = (KS == 16) ? (((blk & 7) << 1) | (blk >> 8)) : (blk & 7);
  const int qt = (blk >> 3) & 31;
  const int kp = N_TOK / KS;
  const int chunks = kp >> 6;
  const int k0 = ks * kp;
  const int q0 = qt * 256;

  // Q fragments (B-operand): lane holds Q[q=l16][c=quad*8+j], 4 q-tiles
  half8v qf[4][4];
#pragma unroll
  for (int t2 = 0; t2 < 4; ++t2) {
    const _Float16* qp = Qf + (size_t)(q0 + w * 64 + t2 * 16 + l16) * DDIM + quad * 8;
#pragma unroll
    for (int kb = 0; kb < 4; ++kb) qf[t2][kb] = *(const half8_ma*)(qp + kb * 32);
  }

  f32x4 O[4][8];
#pragma unroll
  for (int t2 = 0; t2 < 4; ++t2)
#pragma unroll
    for (int vb = 0; vb < 8; ++vb) O[t2][vb] = (f32x4){0.f, 0.f, 0.f, 0.f};
  float ls[4] = {0.f, 0.f, 0.f, 0.f};

  // staging: 4 waves x 4 instrs cover 16 chi slots for K and V each
  const _Float16* srcK[4];
  const _Float16* srcV[4];
  int slot[4];
#pragma unroll
  for (int j = 0; j < 4; ++j) {
    const int chi = w * 4 + j;                  // 0..15
    srcK[j] = Kf + (size_t)(k0 + lane) * DDIM + chi * 8;
    const int t = chi * 64 + lane;
    const int v = t >> 3, h = t & 7;
    const int hs = h ^ ((v >> 1) & 7);          // xor-swizzle granule
    srcV[j] = Vt + (size_t)v * N_TOK + k0 + hs * 8;
    slot[j] = chi * 512;
  }

#pragma unroll
  for (int j = 0; j < 4; ++j) {
    gload_lds16(srcK[j], lds + slot[j]);
    gload_lds16(srcV[j], lds + 8192 + slot[j]);
  }

  for (int ch = 0; ch < chunks; ++ch) {
    __syncthreads();
    _Float16* buf = lds + (ch & 1) * 16384;
    if (ch + 1 < chunks) {
      _Float16* nbuf = lds + ((ch + 1) & 1) * 16384;
      const int adv = (ch + 1) * 64;
#pragma unroll
      for (int j = 0; j < 4; ++j) {
        gload_lds16(srcK[j] + (size_t)adv * DDIM, nbuf + slot[j]);
        gload_lds16(srcV[j] + adv, nbuf + 8192 + slot[j]);
      }
    }
    const _Float16* Ksh = buf;
    const _Float16* Vsh = buf + 8192;

    // S^T = K Q^T : C-layout row=key (quad*4+r), col=q (l16)
    f32x4 S[4][4];
#pragma unroll
    for (int t2 = 0; t2 < 4; ++t2)
#pragma unroll
      for (int cb = 0; cb < 4; ++cb) S[t2][cb] = (f32x4){0.f, 0.f, 0.f, 0.f};
#pragma unroll
    for (int kb = 0; kb < 4; ++kb) {
#pragma unroll
      for (int cb = 0; cb < 4; ++cb) {
        half8v kf = *(const half8_ma*)(Ksh + (((kb * 4 + quad) * 64) + cb * 16 + l16) * 8);
#pragma unroll
        for (int t2 = 0; t2 < 4; ++t2)
          S[t2][cb] = MFMA32(kf, qf[t2][kb], S[t2][cb], 0, 0, 0);
      }
    }

    // P = exp2(S); row-sum via dot2 on the same f16 values PV consumes
    half4v P[4][4];
#pragma unroll
    for (int t2 = 0; t2 < 4; ++t2) {
#pragma unroll
      for (int cb = 0; cb < 4; ++cb) {
        const float p0 = __builtin_amdgcn_exp2f(S[t2][cb][0]);
        const float p1 = __builtin_amdgcn_exp2f(S[t2][cb][1]);
        const float p2 = __builtin_amdgcn_exp2f(S[t2][cb][2]);
        const float p3 = __builtin_amdgcn_exp2f(S[t2][cb][3]);
        half2v lo = pkrtz(p0, p1);
        half2v hi = pkrtz(p2, p3);
        ls[t2] = dot2acc(lo, dot2acc(hi, ls[t2]));
        P[t2][cb] = __builtin_shufflevector(lo, hi, 0, 1, 2, 3);
      }
    }

    // O^T += V^T P^T
#pragma unroll
    for (int cb = 0; cb < 4; ++cb) {
#pragma unroll
      for (int vb = 0; vb < 8; ++vb) {
        const int v = vb * 16 + l16;
        half4v vf = *(const half4_ma*)(Vsh + v * 64 + (((cb * 4 + quad) ^ (l16 & 14)) * 4));
#pragma unroll
        for (int t2 = 0; t2 < 4; ++t2)
          O[t2][vb] = MFMA16(vf, P[t2][cb], O[t2][vb], 0, 0, 0);
      }
    }
  }

  // epilogue
#pragma unroll
  for (int t2 = 0; t2 < 4; ++t2) {
    ls[t2] += __shfl_xor(ls[t2], 16, 64);
    ls[t2] += __shfl_xor(ls[t2], 32, 64);
  }
#pragma unroll
  for (int t2 = 0; t2 < 4; ++t2) {
    const float rl = 1.f / ls[t2];
    const int q = q0 + w * 64 + t2 * 16 + l16;
#pragma unroll
    for (int vb = 0; vb < 8; ++vb) {
#pragma unroll
      for (int r = 0; r < 4; ++r) {
        const int v = vb * 16 + quad * 4 + r;
        Opart[((size_t)ks * DDIM + v) * N_TOK + q] = (_Float16)(O[t2][vb][r] * rl);
      }
    }
  }
  if (lane < 16) {
#pragma unroll
    for (int t2 = 0; t2 < 4; ++t2)
      Lsum[(size_t)ks * N_TOK + q0 + w * 64 + t2 * 16 + lane] = ls[t2];
  }
}

// ---------------- combine: float4, l-weighted average ----------------------
__global__ void combine_kernel(const _Float16* __restrict__ Opart,
                               const float* __restrict__ Lsum,
                               float* __restrict__ out, int KS) {
  const int o4 = (blockIdx.x * 256 + threadIdx.x) * 4;
  const int b = o4 >> 17, v = (o4 >> 10) & 127, p = o4 & 1023;
  const int q = (b << 10) | p;
  float4 num = make_float4(0.f, 0.f, 0.f, 0.f);
  float4 den = make_float4(0.f, 0.f, 0.f, 0.f);
  for (int s = 0; s < KS; ++s) {
    const float4 l = *(const float4_ma*)(Lsum + (size_t)s * N_TOK + q);
    const half4v ov = *(const half4_ma*)(Opart + ((size_t)s * DDIM + v) * N_TOK + q);
    num.x += l.x * (float)ov.x; num.y += l.y * (float)ov.y;
    num.z += l.z * (float)ov.z; num.w += l.w * (float)ov.w;
    den.x += l.x; den.y += l.y; den.z += l.z; den.w += l.w;
  }
  *(float4_ma*)(out + o4) =
      make_float4(num.x / den.x, num.y / den.y, num.z / den.z, num.w / den.w);
}

// ---------------- launch ---------------------------------------------------
extern "C" void kernel_launch(void* const* d_in, const int* in_sizes, int n_in,
                              void* d_out, int out_size, void* d_ws, size_t ws_size,
                              hipStream_t stream) {
  const float* x = (const float*)d_in[0];
  float* out = (float*)d_out;
  char* ws = (char*)d_ws;

  // ws: Qf 2MB | Kf 2MB | Vt 2MB | Opart KS*2MB | Lsum KS*32KB
  const size_t need16 = (6u << 20) + 16 * (2u << 20) + (size_t)16 * N_TOK * 4;
  const int KS = (ws_size >= need16) ? 16 : 8;

  _Float16* Qf    = (_Float16*)(ws);
  _Float16* Kf    = (_Float16*)(ws + (2u << 20));
  _Float16* Vt    = (_Float16*)(ws + (4u << 20));
  _Float16* Opart = (_Float16*)(ws + (6u << 20));
  float*    Lsum  = (float*)(ws + (6u << 20) + (size_t)KS * (2u << 20));

  prep_all<<<dim3(3072), dim3(256), 0, stream>>>(x, Qf, Kf, Vt);
  if (KS == 16) {
    flash_attn<16><<<dim3(512), dim3(256), 0, stream>>>(Qf, Kf, Vt, Opart, Lsum);
  } else {
    flash_attn<8><<<dim3(256), dim3(256), 0, stream>>>(Qf, Kf, Vt, Opart, Lsum);
  }
  combine_kernel<<<dim3(1024), dim3(256), 0, stream>>>(Opart, Lsum, out, KS);
}

// Round 11
// 113.817 us; speedup vs baseline: 1.5151x; 1.4334x over previous
//
#include <hip/hip_runtime.h>
#include <hip/hip_bf16.h>
#include <stdint.h>

#define N_TOK 8192
#define DDIM  128

typedef _Float16 half2v __attribute__((ext_vector_type(2)));
typedef _Float16 half4v __attribute__((ext_vector_type(4)));
typedef _Float16 half8v __attribute__((ext_vector_type(8)));
typedef __fp16  fp16x2 __attribute__((ext_vector_type(2)));
typedef float f32x4 __attribute__((ext_vector_type(4)));
typedef half4v half4_ma __attribute__((may_alias));
typedef half8v half8_ma __attribute__((may_alias));
typedef float4 float4_ma __attribute__((may_alias));

#define MFMA16 __builtin_amdgcn_mfma_f32_16x16x16f16   // legacy spelling
#define MFMA32 __builtin_amdgcn_mfma_f32_16x16x32_f16

// 1/sqrt(128) * log2(e): folded into Q so inner loop is a bare v_exp_f32
#define QSCALE (0.08838834764831845f * 1.4426950408889634f)

__device__ __forceinline__ half2v pkrtz(float a, float b) {
  return __builtin_bit_cast(half2v, __builtin_amdgcn_cvt_pkrtz(a, b));
}

#if __has_builtin(__builtin_amdgcn_fdot2)
__device__ __forceinline__ float dot2acc(half2v a, float c) {
  const fp16x2 ones = {(__fp16)1.f, (__fp16)1.f};
  return __builtin_amdgcn_fdot2(__builtin_bit_cast(fp16x2, a), ones, c, false);
}
#else
__device__ __forceinline__ float dot2acc(half2v a, float c) {
  return c + (float)a.x + (float)a.y;
}
#endif

__device__ __forceinline__ void gload_lds16(const _Float16* g, _Float16* l) {
  __builtin_amdgcn_global_load_lds(
      (const __attribute__((address_space(1))) void*)g,
      (__attribute__((address_space(3))) void*)l, 16, 0, 0);
}

// ---------------- fused prep: Q/K transpose + V copy (one launch) ----------
__global__ void prep_all(const float* __restrict__ x,
                         _Float16* __restrict__ Qf, _Float16* __restrict__ Kf,
                         _Float16* __restrict__ Vt) {
  __shared__ float t[32][33];
  const int blk = blockIdx.x, tid = threadIdx.x;
  if (blk < 2048) {
    const int pt = blk & 31, ct = (blk >> 5) & 3, z = blk >> 7;
    const int b = z >> 1, isQ = z & 1;
    const int c0 = (isQ ? 256 : 128) + ct * 32;
    const int p0 = pt * 32;
    const int tx = tid & 31, ty0 = tid >> 5;
    const float* src = x + ((size_t)b * 384 + c0) * 1024 + p0;
#pragma unroll
    for (int i = 0; i < 4; ++i)
      t[ty0 + i * 8][tx] = src[(ty0 + i * 8) * 1024 + tx];
    __syncthreads();
    _Float16* dst = isQ ? Qf : Kf;
    const float sc = isQ ? QSCALE : 1.f;
#pragma unroll
    for (int i = 0; i < 4; ++i) {
      const int ty = ty0 + i * 8;
      dst[((size_t)b * 1024 + p0 + ty) * DDIM + ct * 32 + tx] = (_Float16)(t[tx][ty] * sc);
    }
  } else {
    const int i4 = ((blk - 2048) * 256 + tid) * 4;
    const int v = i4 >> 13, n = i4 & 8191;
    const int b = n >> 10, p = n & 1023;
    const float4 s = *(const float4_ma*)(x + ((size_t)b * 384 + v) * 1024 + p);
    half4v h; h.x = (_Float16)s.x; h.y = (_Float16)s.y; h.z = (_Float16)s.z; h.w = (_Float16)s.w;
    *(half4_ma*)(Vt + (size_t)v * N_TOK + b * 1024 + p) = h;
  }
}

// ---------------- flash attention: QT=4/wave, CK=32, no spills -------------
// 512 blocks x 256 thr (4 waves x 64 qrows = 256 q/block), KS=16 w/ XCD
// swizzle, 32KB LDS dbuf -> 2 blocks/CU (8 waves). Registers ~250 <= 256.
// LDS per buf: K crumb [chi 16][key 32][clo 8] (4096 f16);
//              V [v 128][pair-swizzled 32] (4096 f16 at +4096).
template<int KS>
__global__ __launch_bounds__(256, 2) void flash_attn(
    const _Float16* __restrict__ Qf, const _Float16* __restrict__ Kf,
    const _Float16* __restrict__ Vt, _Float16* __restrict__ Opart,
    float* __restrict__ Lsum) {
  alignas(16) __shared__ _Float16 lds[16384];  // 2 x (K 8KB + V 8KB) = 32 KB

  const int tid = threadIdx.x;
  const int w = tid >> 6, lane = tid & 63;
  const int quad = lane >> 4, l16 = lane & 15;
  const int blk = blockIdx.x;
  const int ks = (KS == 16) ? (((blk & 7) << 1) | (blk >> 8)) : (blk & 7);
  const int kp = N_TOK / KS;
  const int chunks = kp >> 5;           // CK=32
  const int k0 = ks * kp;
  const int q0 = ((blk >> 3) & 31) * 256;

  // Q fragments resident (B-operand): Q[q=l16][c=quad*8+j], 4 q-tiles
  half8v qf[4][4];
#pragma unroll
  for (int qt = 0; qt < 4; ++qt) {
    const _Float16* qp = Qf + (size_t)(q0 + w * 64 + qt * 16 + l16) * DDIM + quad * 8;
#pragma unroll
    for (int kb = 0; kb < 4; ++kb) qf[qt][kb] = *(const half8_ma*)(qp + kb * 32);
  }

  f32x4 O[4][8];
#pragma unroll
  for (int qt = 0; qt < 4; ++qt)
#pragma unroll
    for (int vb = 0; vb < 8; ++vb) O[qt][vb] = (f32x4){0.f, 0.f, 0.f, 0.f};
  float ls[4] = {0.f, 0.f, 0.f, 0.f};

  // staging: per wave 2 K-instrs + 2 V-instrs per chunk (8+8 per block)
  const _Float16* srcK[2];
  const _Float16* srcV[2];
  int slotK[2], slotV[2];
#pragma unroll
  for (int j = 0; j < 2; ++j) {
    const int i = w * 2 + j;                    // 0..7
    // K: dest chi = i*2 + (lane>>5), key = lane&31 -> linear lane*16B
    srcK[j] = Kf + (size_t)(k0 + (lane & 31)) * DDIM + (i * 2 + (lane >> 5)) * 8;
    slotK[j] = i * 512;
    // V: dest v = i*16 + (lane>>2), pair p = lane&3 -> linear lane*16B;
    // source pair-swizzled: phys p holds logical p ^ ((v>>1)&3)
    const int v = i * 16 + (lane >> 2);
    const int lp = (lane & 3) ^ ((v >> 1) & 3);
    srcV[j] = Vt + (size_t)v * N_TOK + k0 + lp * 8;
    slotV[j] = 4096 + i * 512;
  }

#pragma unroll
  for (int j = 0; j < 2; ++j) {
    gload_lds16(srcK[j], lds + slotK[j]);
    gload_lds16(srcV[j], lds + slotV[j]);
  }

  const int sw = (l16 >> 1) & 3;        // V read un-swizzle key (v>>1)&3
  for (int ch = 0; ch < chunks; ++ch) {
    __syncthreads();
    _Float16* buf = lds + (ch & 1) * 8192;
    if (ch + 1 < chunks) {
      _Float16* nbuf = lds + ((ch + 1) & 1) * 8192;
      const int adv = (ch + 1) * 32;
#pragma unroll
      for (int j = 0; j < 2; ++j) {
        gload_lds16(srcK[j] + (size_t)adv * DDIM, nbuf + slotK[j]);
        gload_lds16(srcV[j] + adv, nbuf + slotV[j]);
      }
    }
    const _Float16* Ksh = buf;
    const _Float16* Vsh = buf + 4096;

    // S^T = K Q^T : C-layout row=key (quad*4+r), col=q (l16); 32 keys -> cb 0..1
    f32x4 S[4][2];
#pragma unroll
    for (int qt = 0; qt < 4; ++qt)
#pragma unroll
      for (int cb = 0; cb < 2; ++cb) S[qt][cb] = (f32x4){0.f, 0.f, 0.f, 0.f};
#pragma unroll
    for (int kb = 0; kb < 4; ++kb) {
#pragma unroll
      for (int cb = 0; cb < 2; ++cb) {
        half8v kf = *(const half8_ma*)(Ksh + ((kb * 4 + quad) * 256 + (cb * 16 + l16) * 8));
#pragma unroll
        for (int qt = 0; qt < 4; ++qt)
          S[qt][cb] = MFMA32(kf, qf[qt][kb], S[qt][cb], 0, 0, 0);
      }
    }

    // P = exp2(S); row-sum via dot2 on the same f16 values PV consumes
    half4v P[4][2];
#pragma unroll
    for (int qt = 0; qt < 4; ++qt) {
#pragma unroll
      for (int cb = 0; cb < 2; ++cb) {
        const float p0 = __builtin_amdgcn_exp2f(S[qt][cb][0]);
        const float p1 = __builtin_amdgcn_exp2f(S[qt][cb][1]);
        const float p2 = __builtin_amdgcn_exp2f(S[qt][cb][2]);
        const float p3 = __builtin_amdgcn_exp2f(S[qt][cb][3]);
        half2v lo = pkrtz(p0, p1);
        half2v hi = pkrtz(p2, p3);
        ls[qt] = dot2acc(lo, dot2acc(hi, ls[qt]));
        P[qt][cb] = __builtin_shufflevector(lo, hi, 0, 1, 2, 3);
      }
    }

    // O^T += V^T P^T : A = V-frag b64 (pair-swizzled), B = P (registers)
#pragma unroll
    for (int cb = 0; cb < 2; ++cb) {
      const int lpair = cb * 2 + (quad >> 1);   // logical 8-key pair
      const int hh = quad & 1;                  // 8B half within pair
#pragma unroll
      for (int vb = 0; vb < 8; ++vb) {
        const int v = vb * 16 + l16;
        const int pp = lpair ^ sw;              // physical pair
        half4v vf = *(const half4_ma*)(Vsh + v * 32 + pp * 8 + hh * 4);
#pragma unroll
        for (int qt = 0; qt < 4; ++qt)
          O[qt][vb] = MFMA16(vf, P[qt][cb], O[qt][vb], 0, 0, 0);
      }
    }
  }

  // epilogue
#pragma unroll
  for (int qt = 0; qt < 4; ++qt) {
    ls[qt] += __shfl_xor(ls[qt], 16, 64);
    ls[qt] += __shfl_xor(ls[qt], 32, 64);
  }
#pragma unroll
  for (int qt = 0; qt < 4; ++qt) {
    const float rl = 1.f / ls[qt];
    const int q = q0 + w * 64 + qt * 16 + l16;
#pragma unroll
    for (int vb = 0; vb < 8; ++vb) {
#pragma unroll
      for (int r = 0; r < 4; ++r) {
        const int v = vb * 16 + quad * 4 + r;
        Opart[((size_t)ks * DDIM + v) * N_TOK + q] = (_Float16)(O[qt][vb][r] * rl);
      }
    }
  }
  if (lane < 16) {
#pragma unroll
    for (int qt = 0; qt < 4; ++qt)
      Lsum[(size_t)ks * N_TOK + q0 + w * 64 + qt * 16 + lane] = ls[qt];
  }
}

// ---------------- combine: float4, l-weighted average ----------------------
__global__ void combine_kernel(const _Float16* __restrict__ Opart,
                               const float* __restrict__ Lsum,
                               float* __restrict__ out, int KS) {
  const int o4 = (blockIdx.x * 256 + threadIdx.x) * 4;
  const int b = o4 >> 17, v = (o4 >> 10) & 127, p = o4 & 1023;
  const int q = (b << 10) | p;
  float4 num = make_float4(0.f, 0.f, 0.f, 0.f);
  float4 den = make_float4(0.f, 0.f, 0.f, 0.f);
  for (int s = 0; s < KS; ++s) {
    const float4 l = *(const float4_ma*)(Lsum + (size_t)s * N_TOK + q);
    const half4v ov = *(const half4_ma*)(Opart + ((size_t)s * DDIM + v) * N_TOK + q);
    num.x += l.x * (float)ov.x; num.y += l.y * (float)ov.y;
    num.z += l.z * (float)ov.z; num.w += l.w * (float)ov.w;
    den.x += l.x; den.y += l.y; den.z += l.z; den.w += l.w;
  }
  *(float4_ma*)(out + o4) =
      make_float4(num.x / den.x, num.y / den.y, num.z / den.z, num.w / den.w);
}

// ---------------- launch ---------------------------------------------------
extern "C" void kernel_launch(void* const* d_in, const int* in_sizes, int n_in,
                              void* d_out, int out_size, void* d_ws, size_t ws_size,
                              hipStream_t stream) {
  const float* x = (const float*)d_in[0];
  float* out = (float*)d_out;
  char* ws = (char*)d_ws;

  // ws: Qf 2MB | Kf 2MB | Vt 2MB | Opart KS*2MB | Lsum KS*32KB
  const size_t need16 = (6u << 20) + 16 * (2u << 20) + (size_t)16 * N_TOK * 4;
  const int KS = (ws_size >= need16) ? 16 : 8;

  _Float16* Qf    = (_Float16*)(ws);
  _Float16* Kf    = (_Float16*)(ws + (2u << 20));
  _Float16* Vt    = (_Float16*)(ws + (4u << 20));
  _Float16* Opart = (_Float16*)(ws + (6u << 20));
  float*    Lsum  = (float*)(ws + (6u << 20) + (size_t)KS * (2u << 20));

  prep_all<<<dim3(3072), dim3(256), 0, stream>>>(x, Qf, Kf, Vt);
  if (KS == 16) {
    flash_attn<16><<<dim3(512), dim3(256), 0, stream>>>(Qf, Kf, Vt, Opart, Lsum);
  } else {
    flash_attn<8><<<dim3(256), dim3(256), 0, stream>>>(Qf, Kf, Vt, Opart, Lsum);
  }
  combine_kernel<<<dim3(1024), dim3(256), 0, stream>>>(Opart, Lsum, out, KS);
}

// Round 12
// 107.712 us; speedup vs baseline: 1.6010x; 1.0567x over previous
//
#include <hip/hip_runtime.h>
#include <hip/hip_bf16.h>
#include <stdint.h>

#define N_TOK 8192
#define DDIM  128

typedef _Float16 half2v __attribute__((ext_vector_type(2)));
typedef _Float16 half4v __attribute__((ext_vector_type(4)));
typedef _Float16 half8v __attribute__((ext_vector_type(8)));
typedef __fp16  fp16x2 __attribute__((ext_vector_type(2)));
typedef float f32x4 __attribute__((ext_vector_type(4)));
typedef half4v half4_ma __attribute__((may_alias));
typedef half8v half8_ma __attribute__((may_alias));
typedef float4 float4_ma __attribute__((may_alias));

#define MFMA32 __builtin_amdgcn_mfma_f32_16x16x32_f16

// 1/sqrt(128) * log2(e): folded into Q so inner loop is a bare v_exp_f32
#define QSCALE (0.08838834764831845f * 1.4426950408889634f)

__device__ __forceinline__ half2v pkrtz(float a, float b) {
  return __builtin_bit_cast(half2v, __builtin_amdgcn_cvt_pkrtz(a, b));
}

#if __has_builtin(__builtin_amdgcn_fdot2)
__device__ __forceinline__ float dot2acc(half2v a, float c) {
  const fp16x2 ones = {(__fp16)1.f, (__fp16)1.f};
  return __builtin_amdgcn_fdot2(__builtin_bit_cast(fp16x2, a), ones, c, false);
}
#else
__device__ __forceinline__ float dot2acc(half2v a, float c) {
  return c + (float)a.x + (float)a.y;
}
#endif

__device__ __forceinline__ void gload_lds16(const _Float16* g, _Float16* l) {
  __builtin_amdgcn_global_load_lds(
      (const __attribute__((address_space(1))) void*)g,
      (__attribute__((address_space(3))) void*)l, 16, 0, 0);
}

// ---------------- fused prep: Q/K transpose + V copy (one launch) ----------
__global__ void prep_all(const float* __restrict__ x,
                         _Float16* __restrict__ Qf, _Float16* __restrict__ Kf,
                         _Float16* __restrict__ Vt) {
  __shared__ float t[32][33];
  const int blk = blockIdx.x, tid = threadIdx.x;
  if (blk < 2048) {
    const int pt = blk & 31, ct = (blk >> 5) & 3, z = blk >> 7;
    const int b = z >> 1, isQ = z & 1;
    const int c0 = (isQ ? 256 : 128) + ct * 32;
    const int p0 = pt * 32;
    const int tx = tid & 31, ty0 = tid >> 5;
    const float* src = x + ((size_t)b * 384 + c0) * 1024 + p0;
#pragma unroll
    for (int i = 0; i < 4; ++i)
      t[ty0 + i * 8][tx] = src[(ty0 + i * 8) * 1024 + tx];
    __syncthreads();
    _Float16* dst = isQ ? Qf : Kf;
    const float sc = isQ ? QSCALE : 1.f;
#pragma unroll
    for (int i = 0; i < 4; ++i) {
      const int ty = ty0 + i * 8;
      dst[((size_t)b * 1024 + p0 + ty) * DDIM + ct * 32 + tx] = (_Float16)(t[tx][ty] * sc);
    }
  } else {
    const int i4 = ((blk - 2048) * 256 + tid) * 4;
    const int v = i4 >> 13, n = i4 & 8191;
    const int b = n >> 10, p = n & 1023;
    const float4 s = *(const float4_ma*)(x + ((size_t)b * 384 + v) * 1024 + p);
    half4v h; h.x = (_Float16)s.x; h.y = (_Float16)s.y; h.z = (_Float16)s.z; h.w = (_Float16)s.w;
    *(half4_ma*)(Vt + (size_t)v * N_TOK + b * 1024 + p) = h;
  }
}

// ---------------- flash attention: QT=4, CK=32, PV at K=32 (sigma trick) ---
// 512 blocks x 256 thr (4 waves x 64 qrows), KS=16 w/ XCD swizzle, 32KB LDS
// dbuf -> 2 blocks/CU. PV contraction index sigma-permuted so S-tile pairs in
// registers ARE the MFMA32 B-operand: sigma(8q+j) = 4q+(j&3)+16*(j>>2).
template<int KS>
__global__ __launch_bounds__(256, 2) void flash_attn(
    const _Float16* __restrict__ Qf, const _Float16* __restrict__ Kf,
    const _Float16* __restrict__ Vt, _Float16* __restrict__ Opart,
    float* __restrict__ Lsum) {
  alignas(16) __shared__ _Float16 lds[16384];  // 2 x (K 8KB + V 8KB) = 32 KB

  const int tid = threadIdx.x;
  const int w = tid >> 6, lane = tid & 63;
  const int quad = lane >> 4, l16 = lane & 15;
  const int blk = blockIdx.x;
  const int ks = (KS == 16) ? (((blk & 7) << 1) | (blk >> 8)) : (blk & 7);
  const int kp = N_TOK / KS;
  const int chunks = kp >> 5;           // CK=32
  const int k0 = ks * kp;
  const int q0 = ((blk >> 3) & 31) * 256;

  // Q fragments resident (B-operand): Q[q=l16][c=quad*8+j], 4 q-tiles
  half8v qf[4][4];
#pragma unroll
  for (int qt = 0; qt < 4; ++qt) {
    const _Float16* qp = Qf + (size_t)(q0 + w * 64 + qt * 16 + l16) * DDIM + quad * 8;
#pragma unroll
    for (int kb = 0; kb < 4; ++kb) qf[qt][kb] = *(const half8_ma*)(qp + kb * 32);
  }

  f32x4 O[4][8];
#pragma unroll
  for (int qt = 0; qt < 4; ++qt)
#pragma unroll
    for (int vb = 0; vb < 8; ++vb) O[qt][vb] = (f32x4){0.f, 0.f, 0.f, 0.f};
  float ls[4] = {0.f, 0.f, 0.f, 0.f};

  // staging: per wave 2 K-instrs + 2 V-instrs per chunk
  const _Float16* srcK[2];
  const _Float16* srcV[2];
  int slotK[2], slotV[2];
#pragma unroll
  for (int j = 0; j < 2; ++j) {
    const int i = w * 2 + j;                    // 0..7
    srcK[j] = Kf + (size_t)(k0 + (lane & 31)) * DDIM + (i * 2 + (lane >> 5)) * 8;
    slotK[j] = i * 512;
    // V: dest v = i*16 + (lane>>2), 16B pair p = lane&3; source pair-swizzled
    const int v = i * 16 + (lane >> 2);
    const int lp = (lane & 3) ^ ((v >> 1) & 3);
    srcV[j] = Vt + (size_t)v * N_TOK + k0 + lp * 8;
    slotV[j] = 4096 + i * 512;
  }

#pragma unroll
  for (int j = 0; j < 2; ++j) {
    gload_lds16(srcK[j], lds + slotK[j]);
    gload_lds16(srcV[j], lds + slotV[j]);
  }

  const int sw = (l16 >> 1) & 3;        // V read un-swizzle key (v>>1)&3
  for (int ch = 0; ch < chunks; ++ch) {
    __syncthreads();
    _Float16* buf = lds + (ch & 1) * 8192;
    if (ch + 1 < chunks) {
      _Float16* nbuf = lds + ((ch + 1) & 1) * 8192;
      const int adv = (ch + 1) * 32;
#pragma unroll
      for (int j = 0; j < 2; ++j) {
        gload_lds16(srcK[j] + (size_t)adv * DDIM, nbuf + slotK[j]);
        gload_lds16(srcV[j] + adv, nbuf + slotV[j]);
      }
    }
    const _Float16* Ksh = buf;
    const _Float16* Vsh = buf + 4096;

    // S^T = K Q^T : C-layout row=key (quad*4+r), col=q (l16); cb = 16-key tile
    f32x4 S[4][2];
#pragma unroll
    for (int qt = 0; qt < 4; ++qt)
#pragma unroll
      for (int cb = 0; cb < 2; ++cb) S[qt][cb] = (f32x4){0.f, 0.f, 0.f, 0.f};
#pragma unroll
    for (int kb = 0; kb < 4; ++kb) {
#pragma unroll
      for (int cb = 0; cb < 2; ++cb) {
        half8v kf = *(const half8_ma*)(Ksh + ((kb * 4 + quad) * 256 + (cb * 16 + l16) * 8));
#pragma unroll
        for (int qt = 0; qt < 4; ++qt)
          S[qt][cb] = MFMA32(kf, qf[qt][kb], S[qt][cb], 0, 0, 0);
      }
    }

    // P = exp2(S); build the full 8-f16 B-operand [cb0 | cb1] directly
    half8v P8[4];
#pragma unroll
    for (int qt = 0; qt < 4; ++qt) {
      const float a0 = __builtin_amdgcn_exp2f(S[qt][0][0]);
      const float a1 = __builtin_amdgcn_exp2f(S[qt][0][1]);
      const float a2 = __builtin_amdgcn_exp2f(S[qt][0][2]);
      const float a3 = __builtin_amdgcn_exp2f(S[qt][0][3]);
      const float b0 = __builtin_amdgcn_exp2f(S[qt][1][0]);
      const float b1 = __builtin_amdgcn_exp2f(S[qt][1][1]);
      const float b2 = __builtin_amdgcn_exp2f(S[qt][1][2]);
      const float b3 = __builtin_amdgcn_exp2f(S[qt][1][3]);
      half2v pa0 = pkrtz(a0, a1), pa1 = pkrtz(a2, a3);
      half2v pb0 = pkrtz(b0, b1), pb1 = pkrtz(b2, b3);
      ls[qt] = dot2acc(pa0, dot2acc(pa1, dot2acc(pb0, dot2acc(pb1, ls[qt]))));
      half4v lo = __builtin_shufflevector(pa0, pa1, 0, 1, 2, 3);
      half4v hi = __builtin_shufflevector(pb0, pb1, 0, 1, 2, 3);
      P8[qt] = __builtin_shufflevector(lo, hi, 0, 1, 2, 3, 4, 5, 6, 7);
    }

    // O^T += V^T P^T via MFMA32 under sigma: lane's A-frag = V keys
    // {4q..4q+3} (half h=quad) and {16+4q..+3} (half h=quad+4), pair-swizzled.
    const int pp1 = (quad >> 1) ^ sw;           // half h=quad   -> 16B pair
    const int pp2 = pp1 ^ 2;                    // half h=quad+4
    const int hh = (quad & 1) * 4;              // 8B half within pair (f16 idx)
#pragma unroll
    for (int vb = 0; vb < 8; ++vb) {
      const int v = vb * 16 + l16;
      half4v lo = *(const half4_ma*)(Vsh + v * 32 + pp1 * 8 + hh);
      half4v hi = *(const half4_ma*)(Vsh + v * 32 + pp2 * 8 + hh);
      half8v vf = __builtin_shufflevector(lo, hi, 0, 1, 2, 3, 4, 5, 6, 7);
#pragma unroll
      for (int qt = 0; qt < 4; ++qt)
        O[qt][vb] = MFMA32(vf, P8[qt], O[qt][vb], 0, 0, 0);
    }
  }

  // epilogue
#pragma unroll
  for (int qt = 0; qt < 4; ++qt) {
    ls[qt] += __shfl_xor(ls[qt], 16, 64);
    ls[qt] += __shfl_xor(ls[qt], 32, 64);
  }
#pragma unroll
  for (int qt = 0; qt < 4; ++qt) {
    const float rl = 1.f / ls[qt];
    const int q = q0 + w * 64 + qt * 16 + l16;
#pragma unroll
    for (int vb = 0; vb < 8; ++vb) {
#pragma unroll
      for (int r = 0; r < 4; ++r) {
        const int v = vb * 16 + quad * 4 + r;
        Opart[((size_t)ks * DDIM + v) * N_TOK + q] = (_Float16)(O[qt][vb][r] * rl);
      }
    }
  }
  if (lane < 16) {
#pragma unroll
    for (int qt = 0; qt < 4; ++qt)
      Lsum[(size_t)ks * N_TOK + q0 + w * 64 + qt * 16 + lane] = ls[qt];
  }
}

// ---------------- combine: float4, l-weighted average ----------------------
__global__ void combine_kernel(const _Float16* __restrict__ Opart,
                               const float* __restrict__ Lsum,
                               float* __restrict__ out, int KS) {
  const int o4 = (blockIdx.x * 256 + threadIdx.x) * 4;
  const int b = o4 >> 17, v = (o4 >> 10) & 127, p = o4 & 1023;
  const int q = (b << 10) | p;
  float4 num = make_float4(0.f, 0.f, 0.f, 0.f);
  float4 den = make_float4(0.f, 0.f, 0.f, 0.f);
  for (int s = 0; s < KS; ++s) {
    const float4 l = *(const float4_ma*)(Lsum + (size_t)s * N_TOK + q);
    const half4v ov = *(const half4_ma*)(Opart + ((size_t)s * DDIM + v) * N_TOK + q);
    num.x += l.x * (float)ov.x; num.y += l.y * (float)ov.y;
    num.z += l.z * (float)ov.z; num.w += l.w * (float)ov.w;
    den.x += l.x; den.y += l.y; den.z += l.z; den.w += l.w;
  }
  *(float4_ma*)(out + o4) =
      make_float4(num.x / den.x, num.y / den.y, num.z / den.z, num.w / den.w);
}

// ---------------- launch ---------------------------------------------------
extern "C" void kernel_launch(void* const* d_in, const int* in_sizes, int n_in,
                              void* d_out, int out_size, void* d_ws, size_t ws_size,
                              hipStream_t stream) {
  const float* x = (const float*)d_in[0];
  float* out = (float*)d_out;
  char* ws = (char*)d_ws;

  // ws: Qf 2MB | Kf 2MB | Vt 2MB | Opart KS*2MB | Lsum KS*32KB
  const size_t need16 = (6u << 20) + 16 * (2u << 20) + (size_t)16 * N_TOK * 4;
  const int KS = (ws_size >= need16) ? 16 : 8;

  _Float16* Qf    = (_Float16*)(ws);
  _Float16* Kf    = (_Float16*)(ws + (2u << 20));
  _Float16* Vt    = (_Float16*)(ws + (4u << 20));
  _Float16* Opart = (_Float16*)(ws + (6u << 20));
  float*    Lsum  = (float*)(ws + (6u << 20) + (size_t)KS * (2u << 20));

  prep_all<<<dim3(3072), dim3(256), 0, stream>>>(x, Qf, Kf, Vt);
  if (KS == 16) {
    flash_attn<16><<<dim3(512), dim3(256), 0, stream>>>(Qf, Kf, Vt, Opart, Lsum);
  } else {
    flash_attn<8><<<dim3(256), dim3(256), 0, stream>>>(Qf, Kf, Vt, Opart, Lsum);
  }
  combine_kernel<<<dim3(1024), dim3(256), 0, stream>>>(Opart, Lsum, out, KS);
}